// Round 8
// baseline (4565.810 us; speedup 1.0000x reference)
//
#include <hip/hip_runtime.h>

// Problem constants: B=4096, K=16, H=32, HM=128, STEPS=8
#define OFF_MS  524288   // local_depths  [B,8,16] = 524288
#define OFF_CS  557056   // march_steps   [B,8,1]  = 32768
#define OFF_IP  1081344  // cossims       [B,8,16] = 524288
#define OFF_CUM 1179648  // implicit_pts  [B,8,3]  = 98304
#define OFF_EPS 1183744  // cum [B,1]=4096, eps [B,1]=4096

struct Params {
  const float *knn, *query, *fw1, *fb1, *fw2, *fb2, *fw3, *fb3, *qkv_w,
    *ptp_w1, *ptp_b1, *ptp_w2, *ptp_b2, *pta_w1, *pta_b1, *pta_w2, *pta_b2,
    *caq_w, *caq_b, *cak_w, *cak_b, *cav_w, *cav_b,
    *cap_w1, *cap_b1, *cap_w2, *cap_b2, *caa_w1, *caa_b1, *caa_w2, *caa_b2,
    *im_w1, *im_b1, *im_w2, *im_b2, *im_w3, *im_b3,
    *ep_w1, *ep_b1, *ep_w2, *ep_b2, *ep_w3, *ep_b3;
  float *o_ld, *o_ms, *o_cs, *o_ip, *o_cum, *o_eps;
};
static_assert(sizeof(Params) == 49 * sizeof(void*), "Params layout");

// EXACT round-4 kernel (best: 2791us), with __launch_bounds__ REMOVED.
// Evidence across rounds: resident blocks/CU == min(resource limit,
// launch_bounds arg2), and compiler VGPR budget ~= 256/arg2 (N=3 -> 84,
// N=4 -> 64: both spill this ~120-VGPR kernel). No-bounds default should
// budget ~128 VGPR (fits) and leave residency to HW limits: LDS 50.7KB ->
// 3 blocks/CU (37.5% occupancy) vs the 2-block cap we've been stuck at.
// Weight loops keep the proven shape: ONE vector load per d-iteration
// (rounds 2/3 restructured loops spilled GBs to scratch).
__global__ void puray_kernel(Params p) {
  const int b = blockIdx.x;
  const int t = threadIdx.x;

  __shared__ float s_wA[4096];        // ptp_w2 (phase C) -> cap_w2 (phase D)
  __shared__ float s_hid[32 * 132];   // hv / hidden slabs, stride 132
  __shared__ float s_rpe[32 * 33];    // rpe (C) / pe (D), stride 33
  __shared__ float s_sim[32 * 33];    // sim rows, stride 33
  __shared__ float s_v[512], s_feats[512];
  __shared__ float s_u[1024];         // C: q[0:512],k[512:1024]; D: kk, vvb
  __shared__ float s_coords[48], s_relv[48], s_reld[16];
  __shared__ float s_qry[3], s_op[3], s_qq[32];
  __shared__ float s_cum;

  {  // stage ptp_w2 into s_wA
    const float4* srcA = (const float4*)p.ptp_w2;
    float4* dA = (float4*)s_wA;
#pragma unroll
    for (int m = 0; m < 4; ++m) dA[t + 256 * m] = srcA[t + 256 * m];
  }
  if (t < 48) s_coords[t] = p.knn[b * 48 + t];
  else if (t < 51) s_qry[t - 48] = p.query[b * 3 + (t - 48)];
  else if (t == 51) s_cum = 0.f;
  else if (t < 55) s_op[t - 52] = 0.f;
  __syncthreads();

  // ---- Phase A: feats = feat_mlp(knn_coords): 16 pts, 3->32->32->32 ----
#pragma unroll
  for (int m = 0; m < 2; ++m) {
    const int l = t + 256 * m, pp = l >> 5, jj = l & 31;
    float a = p.fb1[jj];
#pragma unroll
    for (int c = 0; c < 3; ++c) a = fmaf(s_coords[pp * 3 + c], p.fw1[c * 32 + jj], a);
    s_hid[l] = fmaxf(a, 0.f);
  }
  __syncthreads();
#pragma unroll
  for (int m = 0; m < 2; ++m) {
    const int l = t + 256 * m, pp = l >> 5, jj = l & 31;
    float a = p.fb2[jj];
    for (int i = 0; i < 32; ++i) a = fmaf(s_hid[pp * 32 + i], p.fw2[i * 32 + jj], a);
    s_rpe[l] = fmaxf(a, 0.f);
  }
  __syncthreads();
#pragma unroll
  for (int m = 0; m < 2; ++m) {
    const int l = t + 256 * m, pp = l >> 5, jj = l & 31;
    float a = p.fb3[jj];
    for (int i = 0; i < 32; ++i) a = fmaf(s_rpe[pp * 32 + i], p.fw3[i * 32 + jj], a);
    s_feats[l] = a;
  }
  __syncthreads();

  // ---- Phase B: qkv = feats @ qkv_w ----
#pragma unroll
  for (int m = 0; m < 6; ++m) {
    const int l = t + 256 * m, pp = l / 96, o = l % 96;
    float a = 0.f;
    for (int i = 0; i < 32; ++i) a = fmaf(s_feats[pp * 32 + i], p.qkv_w[i * 96 + o], a);
    if (o < 32) s_u[pp * 32 + o] = a;                 // q
    else if (o < 64) s_u[512 + pp * 32 + o - 32] = a; // k
    else s_v[pp * 32 + o - 64] = a;                   // v
  }
  __syncthreads();

  // ---- Phase C: point transformer, 2 output rows per iteration ----
  for (int ig = 0; ig < 16; ig += 2) {
    const int r = t >> 3;              // pair-row 0..31
    const int i = ig + (r >> 4);
    const int j = r & 15;
    {  // sec1a: rpe hidden hv[32][128] -> s_hid
      const float r0 = s_coords[i * 3 + 0] - s_coords[j * 3 + 0];
      const float r1 = s_coords[i * 3 + 1] - s_coords[j * 3 + 1];
      const float r2 = s_coords[i * 3 + 2] - s_coords[j * 3 + 2];
      const int d0 = (t & 7) * 16;
#pragma unroll
      for (int x = 0; x < 16; ++x) {
        const int d = d0 + x;
        s_hid[r * 132 + d] = fmaxf(fmaf(r0, p.ptp_w1[d],
                              fmaf(r1, p.ptp_w1[128 + d],
                              fmaf(r2, p.ptp_w1[256 + d], p.ptp_b1[d]))), 0.f);
      }
    }
    __syncthreads();
    {  // sec1b: rpe = hv @ ptp_w2(LDS) + b2; simin = q[i]-k[j]+rpe
      const int h0 = (t & 7) * 4;
      float a0 = p.ptp_b2[h0 + 0], a1 = p.ptp_b2[h0 + 1], a2 = p.ptp_b2[h0 + 2], a3 = p.ptp_b2[h0 + 3];
      for (int d = 0; d < 128; ++d) {
        const float hv = s_hid[r * 132 + d];
        const float4 w2 = *(const float4*)&s_wA[d * 32 + h0];
        a0 = fmaf(hv, w2.x, a0); a1 = fmaf(hv, w2.y, a1);
        a2 = fmaf(hv, w2.z, a2); a3 = fmaf(hv, w2.w, a3);
      }
      s_rpe[r * 33 + h0 + 0] = a0; s_rpe[r * 33 + h0 + 1] = a1;
      s_rpe[r * 33 + h0 + 2] = a2; s_rpe[r * 33 + h0 + 3] = a3;
      s_sim[r * 33 + h0 + 0] = s_u[i * 32 + h0 + 0] - s_u[512 + j * 32 + h0 + 0] + a0;
      s_sim[r * 33 + h0 + 1] = s_u[i * 32 + h0 + 1] - s_u[512 + j * 32 + h0 + 1] + a1;
      s_sim[r * 33 + h0 + 2] = s_u[i * 32 + h0 + 2] - s_u[512 + j * 32 + h0 + 2] + a2;
      s_sim[r * 33 + h0 + 3] = s_u[i * 32 + h0 + 3] - s_u[512 + j * 32 + h0 + 3] + a3;
    }
    __syncthreads();
    {  // sec2: hidden2 = relu(simin @ pta_w1(global) + b1) -> s_hid
      const int d0 = (t & 7) * 16;
      float acc[16];
#pragma unroll
      for (int x = 0; x < 16; ++x) acc[x] = p.pta_b1[d0 + x];
      for (int h = 0; h < 32; ++h) {
        const float a = s_sim[r * 33 + h];
        const float4 w0 = *(const float4*)&p.pta_w1[h * 128 + d0];
        const float4 w1v = *(const float4*)&p.pta_w1[h * 128 + d0 + 4];
        const float4 w2v = *(const float4*)&p.pta_w1[h * 128 + d0 + 8];
        const float4 w3v = *(const float4*)&p.pta_w1[h * 128 + d0 + 12];
        acc[0] = fmaf(a, w0.x, acc[0]);   acc[1] = fmaf(a, w0.y, acc[1]);
        acc[2] = fmaf(a, w0.z, acc[2]);   acc[3] = fmaf(a, w0.w, acc[3]);
        acc[4] = fmaf(a, w1v.x, acc[4]);  acc[5] = fmaf(a, w1v.y, acc[5]);
        acc[6] = fmaf(a, w1v.z, acc[6]);  acc[7] = fmaf(a, w1v.w, acc[7]);
        acc[8] = fmaf(a, w2v.x, acc[8]);  acc[9] = fmaf(a, w2v.y, acc[9]);
        acc[10] = fmaf(a, w2v.z, acc[10]); acc[11] = fmaf(a, w2v.w, acc[11]);
        acc[12] = fmaf(a, w3v.x, acc[12]); acc[13] = fmaf(a, w3v.y, acc[13]);
        acc[14] = fmaf(a, w3v.z, acc[14]); acc[15] = fmaf(a, w3v.w, acc[15]);
      }
#pragma unroll
      for (int x = 0; x < 16; ++x) s_hid[r * 132 + d0 + x] = fmaxf(acc[x], 0.f);
    }
    __syncthreads();
    {  // sec3: sim = hidden2 @ pta_w2(global stream) + b2
      const int h0 = (t & 7) * 4;
      float a0 = p.pta_b2[h0 + 0], a1 = p.pta_b2[h0 + 1], a2 = p.pta_b2[h0 + 2], a3 = p.pta_b2[h0 + 3];
      for (int d = 0; d < 128; ++d) {
        const float a = s_hid[r * 132 + d];
        const float4 w2 = *(const float4*)&p.pta_w2[d * 32 + h0];
        a0 = fmaf(a, w2.x, a0); a1 = fmaf(a, w2.y, a1);
        a2 = fmaf(a, w2.z, a2); a3 = fmaf(a, w2.w, a3);
      }
      s_sim[r * 33 + h0 + 0] = a0; s_sim[r * 33 + h0 + 1] = a1;
      s_sim[r * 33 + h0 + 2] = a2; s_sim[r * 33 + h0 + 3] = a3;
    }
    __syncthreads();
    if (t < 64) {  // sec4: softmax over j, weighted sum with (v + rpe)
      const int g2 = t >> 5, h = t & 31;
      float mx = -1e30f;
#pragma unroll
      for (int j2 = 0; j2 < 16; ++j2) mx = fmaxf(mx, s_sim[(g2 * 16 + j2) * 33 + h]);
      float sum = 0.f, o = 0.f;
#pragma unroll
      for (int j2 = 0; j2 < 16; ++j2) {
        const float e = __expf(s_sim[(g2 * 16 + j2) * 33 + h] - mx);
        sum += e;
        o = fmaf(e, s_v[j2 * 32 + h] + s_rpe[(g2 * 16 + j2) * 33 + h], o);
      }
      s_feats[(ig + g2) * 32 + h] = o / sum;
    }
    __syncthreads();
  }

  // ---- restage s_wA <- cap_w2; hoisted kk/vv into s_u ----
  {
    const float4* srcA = (const float4*)p.cap_w2;
    float4* dA = (float4*)s_wA;
#pragma unroll
    for (int m = 0; m < 4; ++m) dA[t + 256 * m] = srcA[t + 256 * m];
  }
#pragma unroll
  for (int m = 0; m < 2; ++m) {
    const int l = t + 256 * m, k = l >> 5, h = l & 31;
    float akk = p.cak_b[h], avv = p.cav_b[h];
    for (int i = 0; i < 32; ++i) {
      const float f = s_feats[k * 32 + i];
      akk = fmaf(f, p.cak_w[i * 32 + h], akk);
      avv = fmaf(f, p.cav_w[i * 32 + h], avv);
    }
    s_u[k * 32 + h] = akk;        // kk
    s_u[512 + k * 32 + h] = avv;  // vv base
  }
  __syncthreads();

  // ---- Phase D: 8 march steps + final epilogue (s==8) ----
  for (int s = 0; s <= 8; ++s) {
    float rv0 = 0.f, rv1 = 0.f, rv2 = 0.f;  // lanes<16: rel unit vec (regs)
    {  // secA: pe hidden hv[16][128] -> s_hid (all threads)
      const int k = t >> 4, d0 = (t & 15) * 8;
      float c0, c1, c2;
      if (s < 8) {
        c0 = s_coords[k * 3 + 0] - s_op[0];
        c1 = s_coords[k * 3 + 1] - s_op[1];
        c2 = s_coords[k * 3 + 2] - s_op[2];
      } else {  // stale rel from step 7 (reference semantics)
        const float rd = s_reld[k];
        c0 = s_relv[k * 3 + 0] * rd; c1 = s_relv[k * 3 + 1] * rd; c2 = s_relv[k * 3 + 2] * rd;
      }
#pragma unroll
      for (int x = 0; x < 8; ++x) {
        const int d = d0 + x;
        s_hid[k * 132 + d] = fmaxf(fmaf(c0, p.cap_w1[d],
                              fmaf(c1, p.cap_w1[128 + d],
                              fmaf(c2, p.cap_w1[256 + d], p.cap_b1[d]))), 0.f);
      }
    }
    if (t < 64) {  // wave0: rel/o_ld + shuffle-broadcast feat_mlp chain -> qq
      const int h = t & 31;
      if (s < 8 && t < 16) {
        const float r0 = s_coords[t * 3 + 0] - s_op[0];
        const float r1 = s_coords[t * 3 + 1] - s_op[1];
        const float r2 = s_coords[t * 3 + 2] - s_op[2];
        const float rd = sqrtf(r0 * r0 + r1 * r1 + r2 * r2);
        const float inv = 1.f / rd;
        rv0 = r0 * inv; rv1 = r1 * inv; rv2 = r2 * inv;
        s_reld[t] = rd;
        s_relv[t * 3 + 0] = rv0; s_relv[t * 3 + 1] = rv1; s_relv[t * 3 + 2] = rv2;
        p.o_ld[b * 128 + s * 16 + t] = rd;
      }
      float opc0, opc1, opc2;
      if (s < 8) {
        const float cum = s_cum;
        opc0 = s_qry[0] * cum; opc1 = s_qry[1] * cum; opc2 = s_qry[2] * cum;
      } else {
        opc0 = s_op[0]; opc1 = s_op[1]; opc2 = s_op[2];
      }
      float v1 = fmaxf(fmaf(opc0, p.fw1[h],
                    fmaf(opc1, p.fw1[32 + h],
                    fmaf(opc2, p.fw1[64 + h], p.fb1[h]))), 0.f);
      float a = p.fb2[h];
      for (int i2 = 0; i2 < 32; ++i2) a = fmaf(__shfl(v1, i2), p.fw2[i2 * 32 + h], a);
      const float v2 = fmaxf(a, 0.f);
      a = p.fb3[h];
      for (int i2 = 0; i2 < 32; ++i2) a = fmaf(__shfl(v2, i2), p.fw3[i2 * 32 + h], a);
      const float opf = a;
      a = p.caq_b[h];
      for (int i2 = 0; i2 < 32; ++i2) a = fmaf(__shfl(opf, i2), p.caq_w[i2 * 32 + h], a);
      if (t < 32) s_qq[h] = a;
    }
    __syncthreads();
    {  // secB: pe = hv @ cap_w2(LDS) + b2 -> s_rpe
      const int k = t >> 4, h0 = (t & 15) * 2;
      float a0 = p.cap_b2[h0], a1 = p.cap_b2[h0 + 1];
      for (int d = 0; d < 128; ++d) {
        const float hv = s_hid[k * 132 + d];
        const float2 w2 = *(const float2*)&s_wA[d * 32 + h0];
        a0 = fmaf(hv, w2.x, a0); a1 = fmaf(hv, w2.y, a1);
      }
      s_rpe[k * 33 + h0] = a0; s_rpe[k * 33 + h0 + 1] = a1;
    }
    __syncthreads();
    {  // secC: attn hidden = relu((qq-kk+pe) @ caa_w1(global) + b1) -> s_hid
      const int k = t >> 4, d0 = (t & 15) * 8;
      float acc[8];
#pragma unroll
      for (int x = 0; x < 8; ++x) acc[x] = p.caa_b1[d0 + x];
      for (int h = 0; h < 32; ++h) {
        const float ain = s_qq[h] - s_u[k * 32 + h] + s_rpe[k * 33 + h];
        const float4 w0 = *(const float4*)&p.caa_w1[h * 128 + d0];
        const float4 w1v = *(const float4*)&p.caa_w1[h * 128 + d0 + 4];
        acc[0] = fmaf(ain, w0.x, acc[0]);  acc[1] = fmaf(ain, w0.y, acc[1]);
        acc[2] = fmaf(ain, w0.z, acc[2]);  acc[3] = fmaf(ain, w0.w, acc[3]);
        acc[4] = fmaf(ain, w1v.x, acc[4]); acc[5] = fmaf(ain, w1v.y, acc[5]);
        acc[6] = fmaf(ain, w1v.z, acc[6]); acc[7] = fmaf(ain, w1v.w, acc[7]);
      }
#pragma unroll
      for (int x = 0; x < 8; ++x) s_hid[k * 132 + d0 + x] = fmaxf(acc[x], 0.f);
    }
    __syncthreads();
    {  // secD: attn sim = hidden @ caa_w2(global stream) + b2 -> s_sim
      const int k = t >> 4, h0 = (t & 15) * 2;
      float a0 = p.caa_b2[h0], a1 = p.caa_b2[h0 + 1];
      for (int d = 0; d < 128; ++d) {
        const float hv = s_hid[k * 132 + d];
        const float2 w2 = *(const float2*)&p.caa_w2[d * 32 + h0];
        a0 = fmaf(hv, w2.x, a0); a1 = fmaf(hv, w2.y, a1);
      }
      s_sim[k * 33 + h0] = a0; s_sim[k * 33 + h0 + 1] = a1;
    }
    __syncthreads();
    if (t < 64) {  // secE: softmax + ca + (im chain | ep chain) on wave0
      const int h = t & 31;
      float mx = -1e30f;
#pragma unroll
      for (int k = 0; k < 16; ++k) mx = fmaxf(mx, s_sim[k * 33 + h]);
      float sum = 0.f, o = 0.f;
#pragma unroll
      for (int k = 0; k < 16; ++k) {
        const float e = __expf(s_sim[k * 33 + h] - mx);
        sum += e;
        o = fmaf(e, s_u[512 + k * 32 + h] + s_rpe[k * 33 + h], o);
      }
      const float ca = o / sum;
      if (s < 8) {
        float a = p.im_b1[h];
        for (int i2 = 0; i2 < 32; ++i2) a = fmaf(__shfl(ca, i2), p.im_w1[i2 * 32 + h], a);
        const float m1 = fmaxf(a, 0.f);
        a = p.im_b2[h];
        for (int i2 = 0; i2 < 32; ++i2) a = fmaf(__shfl(m1, i2), p.im_w2[i2 * 32 + h], a);
        const float m2 = fmaxf(a, 0.f);
        float p0 = m2 * p.im_w3[h * 3 + 0];
        float p1 = m2 * p.im_w3[h * 3 + 1];
        float p2 = m2 * p.im_w3[h * 3 + 2];
#pragma unroll
        for (int m = 1; m < 32; m <<= 1) {
          p0 += __shfl_xor(p0, m, 32);
          p1 += __shfl_xor(p1, m, 32);
          p2 += __shfl_xor(p2, m, 32);
        }
        p0 += p.im_b3[0]; p1 += p.im_b3[1]; p2 += p.im_b3[2];
        const float step = sqrtf(p0 * p0 + p1 * p1 + p2 * p2);
        const float cum = s_cum;
        const float opc0 = s_qry[0] * cum, opc1 = s_qry[1] * cum, opc2 = s_qry[2] * cum;
        const float inv = 1.f / step;
        const float tg0 = p0 * inv, tg1 = p1 * inv, tg2 = p2 * inv;
        if (t == 0) {
          p.o_ms[b * 8 + s] = step;
          p.o_ip[(b * 8 + s) * 3 + 0] = opc0 + p0;
          s_op[0] = opc0 + s_qry[0] * step;
        } else if (t == 1) {
          p.o_ip[(b * 8 + s) * 3 + 1] = opc1 + p1;
          s_op[1] = opc1 + s_qry[1] * step;
        } else if (t == 2) {
          p.o_ip[(b * 8 + s) * 3 + 2] = opc2 + p2;
          s_op[2] = opc2 + s_qry[2] * step;
        } else if (t == 3) {
          s_cum = cum + step;
        }
        if (t < 16) {
          p.o_cs[b * 128 + s * 16 + t] = tg0 * rv0 + tg1 * rv1 + tg2 * rv2;
        }
      } else {
        float a = p.ep_b1[h];
        for (int i2 = 0; i2 < 32; ++i2) a = fmaf(__shfl(ca, i2), p.ep_w1[i2 * 32 + h], a);
        a = fmaf(s_qry[0], p.ep_w1[1024 + h], a);
        a = fmaf(s_qry[1], p.ep_w1[1056 + h], a);
        a = fmaf(s_qry[2], p.ep_w1[1088 + h], a);
        const float e1 = fmaxf(a, 0.f);
        a = p.ep_b2[h];
        for (int i2 = 0; i2 < 32; ++i2) a = fmaf(__shfl(e1, i2), p.ep_w2[i2 * 32 + h], a);
        const float e2 = fmaxf(a, 0.f);
        float pp = e2 * p.ep_w3[h];
#pragma unroll
        for (int m = 1; m < 32; m <<= 1) pp += __shfl_xor(pp, m, 32);
        if (t == 0) {
          p.o_eps[b] = pp + p.ep_b3[0];
          p.o_cum[b] = s_cum;
        }
      }
    }
    __syncthreads();
  }
}

extern "C" void kernel_launch(void* const* d_in, const int* in_sizes, int n_in,
                              void* d_out, int out_size, void* d_ws, size_t ws_size,
                              hipStream_t stream) {
  Params p;
  const float** f = (const float**)(void*)&p;
  for (int i = 0; i < 43; ++i) f[i] = (const float*)d_in[i];
  float* out = (float*)d_out;
  p.o_ld  = out;
  p.o_ms  = out + OFF_MS;
  p.o_cs  = out + OFF_CS;
  p.o_ip  = out + OFF_IP;
  p.o_cum = out + OFF_CUM;
  p.o_eps = out + OFF_EPS;
  puray_kernel<<<dim3(4096), dim3(256), 0, stream>>>(p);
}

// Round 9
// 872.853 us; speedup vs baseline: 5.2309x; 5.2309x over previous
//
#include <hip/hip_runtime.h>

// Problem constants: B=4096, K=16, H=32, HM=128, STEPS=8
#define OFF_MS  524288
#define OFF_CS  557056
#define OFF_IP  1081344
#define OFF_CUM 1179648
#define OFF_EPS 1183744

struct Params {
  const float *knn, *query, *fw1, *fb1, *fw2, *fb2, *fw3, *fb3, *qkv_w,
    *ptp_w1, *ptp_b1, *ptp_w2, *ptp_b2, *pta_w1, *pta_b1, *pta_w2, *pta_b2,
    *caq_w, *caq_b, *cak_w, *cak_b, *cav_w, *cav_b,
    *cap_w1, *cap_b1, *cap_w2, *cap_b2, *caa_w1, *caa_b1, *caa_w2, *caa_b2,
    *im_w1, *im_b1, *im_w2, *im_b2, *im_w3, *im_b3,
    *ep_w1, *ep_b1, *ep_w2, *ep_b2, *ep_w3, *ep_b3;
  float *o_ld, *o_ms, *o_cs, *o_ip, *o_cum, *o_eps;
};
static_assert(sizeof(Params) == 49 * sizeof(void*), "Params layout");

typedef float f32x4 __attribute__((ext_vector_type(4)));
typedef unsigned short u16x8 __attribute__((ext_vector_type(8)));

__device__ __forceinline__ unsigned short f2b(float x) {  // fp32->bf16 RNE
  unsigned u = __float_as_uint(x);
  u += 0x7fffu + ((u >> 16) & 1u);
  return (unsigned short)(u >> 16);
}
__device__ __forceinline__ unsigned pack2(float lo, float hi) {
  return (unsigned)f2b(lo) | ((unsigned)f2b(hi) << 16);
}

// D(16x16) += A(16x32,bf16) * B(32x16,bf16). s_nop guards VALU->SrcC hazard;
// fence guards MFMA-write -> VALU-read. A: row=lane&15,k=(lane>>4)*8+i;
// B: col=lane&15,k=(lane>>4)*8+i (B stored transposed [N][K]);
// C/D: col=lane&15,row=(lane>>4)*4+reg  [m89-verified].
#define MFMA(acc, a, bb) \
  asm volatile("s_nop 2\n\tv_mfma_f32_16x16x32_bf16 %0, %1, %2, %0" \
               : "+v"(acc) : "v"(a), "v"(bb))
#define MFMA_FENCE(acc) asm volatile("s_nop 7\n\ts_nop 7" : "+v"(acc))

// MFMA rewrite of the 6 GEMM sections; scalar/softmax scaffolding = round 4.
// (256,2): the only no-spill config on this toolchain (rounds 2/3/6/8).
__launch_bounds__(256, 2)
__global__ void puray_kernel(Params p) {
  const int b = blockIdx.x;
  const int t = threadIdx.x;
  const int w = t >> 6, l = t & 63;
  const int ln16 = l & 15, kg = l >> 4, k0 = kg * 8;

  __shared__ __align__(16) unsigned short s_wTA[32 * 128];  // [n][k] ptp_w2T -> cap_w2T
  __shared__ __align__(16) unsigned short s_wTB[128 * 32];  // [n][k] pta_w1T -> caa_w1T
  __shared__ __align__(16) unsigned short s_wTC[32 * 128];  // [n][k] pta_w2T -> caa_w2T
  __shared__ __align__(16) unsigned short s_hidb[32 * 128]; // bf16 act [row][128]
  __shared__ __align__(16) unsigned short s_simb[32 * 32];  // bf16 act [row][32]
  __shared__ float s_rpe[32 * 33];    // fp32 rpe/pe (stride 33); also phase-A h1
  __shared__ float s_sim[32 * 33];    // fp32 sim rows; also phase-A h2
  __shared__ float s_v[512], s_feats[512];
  __shared__ float s_u[1024];         // C: q|k ; D: kk|vvb
  __shared__ float s_coords[48], s_relv[48], s_reld[16];
  __shared__ float s_qry[3], s_op[3], s_qq[32];
  __shared__ float s_cum;

  // ---- stage: transpose+convert phase-C weights to bf16 [N][K] ----
#pragma unroll 4
  for (int m = 0; m < 16; ++m) {
    const int idx = t + 256 * m;
    { const int n = idx >> 7, k = idx & 127;
      s_wTA[idx] = f2b(p.ptp_w2[k * 32 + n]);
      s_wTC[idx] = f2b(p.pta_w2[k * 32 + n]); }
    { const int n = idx >> 5, k = idx & 31;
      s_wTB[idx] = f2b(p.pta_w1[k * 128 + n]); }
  }
  if (t < 48) s_coords[t] = p.knn[b * 48 + t];
  else if (t < 51) s_qry[t - 48] = p.query[b * 3 + (t - 48)];
  else if (t == 51) s_cum = 0.f;
  else if (t < 55) s_op[t - 52] = 0.f;
  __syncthreads();

  // ---- Phase A: feats (scratch: s_rpe=h1, s_sim=h2) ----
#pragma unroll
  for (int m = 0; m < 2; ++m) {
    const int l2 = t + 256 * m, pp = l2 >> 5, jj = l2 & 31;
    float a = p.fb1[jj];
#pragma unroll
    for (int c = 0; c < 3; ++c) a = fmaf(s_coords[pp * 3 + c], p.fw1[c * 32 + jj], a);
    s_rpe[l2] = fmaxf(a, 0.f);
  }
  __syncthreads();
#pragma unroll
  for (int m = 0; m < 2; ++m) {
    const int l2 = t + 256 * m, pp = l2 >> 5, jj = l2 & 31;
    float a = p.fb2[jj];
    for (int i = 0; i < 32; ++i) a = fmaf(s_rpe[pp * 32 + i], p.fw2[i * 32 + jj], a);
    s_sim[l2] = fmaxf(a, 0.f);
  }
  __syncthreads();
#pragma unroll
  for (int m = 0; m < 2; ++m) {
    const int l2 = t + 256 * m, pp = l2 >> 5, jj = l2 & 31;
    float a = p.fb3[jj];
    for (int i = 0; i < 32; ++i) a = fmaf(s_sim[pp * 32 + i], p.fw3[i * 32 + jj], a);
    s_feats[l2] = a;
  }
  __syncthreads();

  // ---- Phase B: qkv ----
#pragma unroll
  for (int m = 0; m < 6; ++m) {
    const int l2 = t + 256 * m, pp = l2 / 96, o = l2 % 96;
    float a = 0.f;
    for (int i = 0; i < 32; ++i) a = fmaf(s_feats[pp * 32 + i], p.qkv_w[i * 96 + o], a);
    if (o < 32) s_u[pp * 32 + o] = a;
    else if (o < 64) s_u[512 + pp * 32 + o - 32] = a;
    else s_v[pp * 32 + o - 64] = a;
  }
  __syncthreads();

  // ---- Phase C: 2 output rows per iteration, MFMA GEMMs ----
  for (int ig = 0; ig < 16; ig += 2) {
    {  // sec1a: hv[32][128] -> s_hidb (bf16)
      const int r = t >> 3;
      const int i = ig + (r >> 4), j = r & 15;
      const float r0 = s_coords[i * 3 + 0] - s_coords[j * 3 + 0];
      const float r1 = s_coords[i * 3 + 1] - s_coords[j * 3 + 1];
      const float r2 = s_coords[i * 3 + 2] - s_coords[j * 3 + 2];
      const int d0 = (t & 7) * 16;
#pragma unroll
      for (int x = 0; x < 16; x += 2) {
        const int d = d0 + x;
        const float h0v = fmaxf(fmaf(r0, p.ptp_w1[d],
                           fmaf(r1, p.ptp_w1[128 + d],
                           fmaf(r2, p.ptp_w1[256 + d], p.ptp_b1[d]))), 0.f);
        const float h1v = fmaxf(fmaf(r0, p.ptp_w1[d + 1],
                           fmaf(r1, p.ptp_w1[128 + d + 1],
                           fmaf(r2, p.ptp_w1[256 + d + 1], p.ptp_b1[d + 1]))), 0.f);
        ((unsigned*)s_hidb)[(r * 128 + d) >> 1] = pack2(h0v, h1v);
      }
    }
    __syncthreads();
    {  // G1: rpe[32][32] = hv @ ptp_w2 + b2 ; simin = q[i]-k[j]+rpe -> s_simb
      const int mb = w >> 1, nb = w & 1, n = nb * 16 + ln16;
      const float bias = p.ptp_b2[n];
      f32x4 acc = {bias, bias, bias, bias};
#pragma unroll
      for (int kk = 0; kk < 4; ++kk) {
        const u16x8 a = *(const u16x8*)&s_hidb[(mb * 16 + ln16) * 128 + kk * 32 + k0];
        const u16x8 bb = *(const u16x8*)&s_wTA[n * 128 + kk * 32 + k0];
        MFMA(acc, a, bb);
      }
      MFMA_FENCE(acc);
#pragma unroll
      for (int r2 = 0; r2 < 4; ++r2) {
        const int row = mb * 16 + kg * 4 + r2;
        const float val = acc[r2];
        s_rpe[row * 33 + n] = val;
        const int i = ig + (row >> 4), j = row & 15;
        s_simb[row * 32 + n] = f2b(s_u[i * 32 + n] - s_u[512 + j * 32 + n] + val);
      }
    }
    __syncthreads();
    {  // G2: hid[32][128] = relu(simin @ pta_w1 + b1) -> s_hidb
      const int mb = w & 1;
      const u16x8 a = *(const u16x8*)&s_simb[(mb * 16 + ln16) * 32 + k0];
#pragma unroll
      for (int j2 = 0; j2 < 4; ++j2) {
        const int n = ((w >> 1) * 4 + j2) * 16 + ln16;
        const u16x8 bb = *(const u16x8*)&s_wTB[n * 32 + k0];
        const float bias = p.pta_b1[n];
        f32x4 acc = {bias, bias, bias, bias};
        MFMA(acc, a, bb);
        MFMA_FENCE(acc);
#pragma unroll
        for (int r2 = 0; r2 < 4; ++r2)
          s_hidb[(mb * 16 + kg * 4 + r2) * 128 + n] = f2b(fmaxf(acc[r2], 0.f));
      }
    }
    __syncthreads();
    {  // G3: sim[32][32] = hid @ pta_w2 + b2 -> s_sim (fp32)
      const int mb = w >> 1, nb = w & 1, n = nb * 16 + ln16;
      const float bias = p.pta_b2[n];
      f32x4 acc = {bias, bias, bias, bias};
#pragma unroll
      for (int kk = 0; kk < 4; ++kk) {
        const u16x8 a = *(const u16x8*)&s_hidb[(mb * 16 + ln16) * 128 + kk * 32 + k0];
        const u16x8 bb = *(const u16x8*)&s_wTC[n * 128 + kk * 32 + k0];
        MFMA(acc, a, bb);
      }
      MFMA_FENCE(acc);
#pragma unroll
      for (int r2 = 0; r2 < 4; ++r2) s_sim[(mb * 16 + kg * 4 + r2) * 33 + n] = acc[r2];
    }
    __syncthreads();
    if (t < 64) {  // sec4: softmax + weighted sum (fp32, unchanged)
      const int g2 = t >> 5, h = t & 31;
      float mx = -1e30f;
#pragma unroll
      for (int j2 = 0; j2 < 16; ++j2) mx = fmaxf(mx, s_sim[(g2 * 16 + j2) * 33 + h]);
      float sum = 0.f, o = 0.f;
#pragma unroll
      for (int j2 = 0; j2 < 16; ++j2) {
        const float e = __expf(s_sim[(g2 * 16 + j2) * 33 + h] - mx);
        sum += e;
        o = fmaf(e, s_v[j2 * 32 + h] + s_rpe[(g2 * 16 + j2) * 33 + h], o);
      }
      s_feats[(ig + g2) * 32 + h] = o / sum;
    }
    __syncthreads();
  }

  // ---- restage weights (cap/caa) + hoisted kk/vv ----
#pragma unroll 4
  for (int m = 0; m < 16; ++m) {
    const int idx = t + 256 * m;
    { const int n = idx >> 7, k = idx & 127;
      s_wTA[idx] = f2b(p.cap_w2[k * 32 + n]);
      s_wTC[idx] = f2b(p.caa_w2[k * 32 + n]); }
    { const int n = idx >> 5, k = idx & 31;
      s_wTB[idx] = f2b(p.caa_w1[k * 128 + n]); }
  }
#pragma unroll
  for (int m = 0; m < 2; ++m) {
    const int l2 = t + 256 * m, k = l2 >> 5, h = l2 & 31;
    float akk = p.cak_b[h], avv = p.cav_b[h];
    for (int i = 0; i < 32; ++i) {
      const float f = s_feats[k * 32 + i];
      akk = fmaf(f, p.cak_w[i * 32 + h], akk);
      avv = fmaf(f, p.cav_w[i * 32 + h], avv);
    }
    s_u[k * 32 + h] = akk;
    s_u[512 + k * 32 + h] = avv;
  }
  __syncthreads();

  // ---- Phase D: 8 march steps + epilogue ----
  for (int s = 0; s <= 8; ++s) {
    float rv0 = 0.f, rv1 = 0.f, rv2 = 0.f;
    {  // secA: hv[16][128] -> s_hidb (bf16)
      const int k = t >> 4, d0 = (t & 15) * 8;
      float c0, c1, c2;
      if (s < 8) {
        c0 = s_coords[k * 3 + 0] - s_op[0];
        c1 = s_coords[k * 3 + 1] - s_op[1];
        c2 = s_coords[k * 3 + 2] - s_op[2];
      } else {
        const float rd = s_reld[k];
        c0 = s_relv[k * 3 + 0] * rd; c1 = s_relv[k * 3 + 1] * rd; c2 = s_relv[k * 3 + 2] * rd;
      }
#pragma unroll
      for (int x = 0; x < 8; x += 2) {
        const int d = d0 + x;
        const float h0v = fmaxf(fmaf(c0, p.cap_w1[d],
                           fmaf(c1, p.cap_w1[128 + d],
                           fmaf(c2, p.cap_w1[256 + d], p.cap_b1[d]))), 0.f);
        const float h1v = fmaxf(fmaf(c0, p.cap_w1[d + 1],
                           fmaf(c1, p.cap_w1[128 + d + 1],
                           fmaf(c2, p.cap_w1[256 + d + 1], p.cap_b1[d + 1]))), 0.f);
        ((unsigned*)s_hidb)[(k * 128 + d) >> 1] = pack2(h0v, h1v);
      }
    }
    if (t < 64) {  // wave0: rel/o_ld + shuffle feat_mlp chain -> s_qq
      const int h = t & 31;
      if (s < 8 && t < 16) {
        const float r0 = s_coords[t * 3 + 0] - s_op[0];
        const float r1 = s_coords[t * 3 + 1] - s_op[1];
        const float r2 = s_coords[t * 3 + 2] - s_op[2];
        const float rd = sqrtf(r0 * r0 + r1 * r1 + r2 * r2);
        const float inv = 1.f / rd;
        rv0 = r0 * inv; rv1 = r1 * inv; rv2 = r2 * inv;
        s_reld[t] = rd;
        s_relv[t * 3 + 0] = rv0; s_relv[t * 3 + 1] = rv1; s_relv[t * 3 + 2] = rv2;
        p.o_ld[b * 128 + s * 16 + t] = rd;
      }
      float opc0, opc1, opc2;
      if (s < 8) {
        const float cum = s_cum;
        opc0 = s_qry[0] * cum; opc1 = s_qry[1] * cum; opc2 = s_qry[2] * cum;
      } else {
        opc0 = s_op[0]; opc1 = s_op[1]; opc2 = s_op[2];
      }
      float v1 = fmaxf(fmaf(opc0, p.fw1[h],
                    fmaf(opc1, p.fw1[32 + h],
                    fmaf(opc2, p.fw1[64 + h], p.fb1[h]))), 0.f);
      float a = p.fb2[h];
      for (int i2 = 0; i2 < 32; ++i2) a = fmaf(__shfl(v1, i2), p.fw2[i2 * 32 + h], a);
      const float v2 = fmaxf(a, 0.f);
      a = p.fb3[h];
      for (int i2 = 0; i2 < 32; ++i2) a = fmaf(__shfl(v2, i2), p.fw3[i2 * 32 + h], a);
      const float opf = a;
      a = p.caq_b[h];
      for (int i2 = 0; i2 < 32; ++i2) a = fmaf(__shfl(opf, i2), p.caq_w[i2 * 32 + h], a);
      if (t < 32) s_qq[h] = a;
    }
    __syncthreads();
    if (w < 2) {  // secB: pe[16][32] = hv @ cap_w2 + b2; fused ain -> s_simb
      const int n = w * 16 + ln16;
      const float bias = p.cap_b2[n];
      f32x4 acc = {bias, bias, bias, bias};
#pragma unroll
      for (int kk = 0; kk < 4; ++kk) {
        const u16x8 a = *(const u16x8*)&s_hidb[ln16 * 128 + kk * 32 + k0];
        const u16x8 bb = *(const u16x8*)&s_wTA[n * 128 + kk * 32 + k0];
        MFMA(acc, a, bb);
      }
      MFMA_FENCE(acc);
#pragma unroll
      for (int r2 = 0; r2 < 4; ++r2) {
        const int row = kg * 4 + r2;
        const float pe = acc[r2];
        s_rpe[row * 33 + n] = pe;
        s_simb[row * 32 + n] = f2b(s_qq[n] - s_u[row * 32 + n] + pe);
      }
    }
    __syncthreads();
    {  // secC: hid[16][128] = relu(ain @ caa_w1 + b1) -> s_hidb
      const u16x8 a = *(const u16x8*)&s_simb[ln16 * 32 + k0];
#pragma unroll
      for (int j2 = 0; j2 < 2; ++j2) {
        const int n = (w * 2 + j2) * 16 + ln16;
        const u16x8 bb = *(const u16x8*)&s_wTB[n * 32 + k0];
        const float bias = p.caa_b1[n];
        f32x4 acc = {bias, bias, bias, bias};
        MFMA(acc, a, bb);
        MFMA_FENCE(acc);
#pragma unroll
        for (int r2 = 0; r2 < 4; ++r2)
          s_hidb[(kg * 4 + r2) * 128 + n] = f2b(fmaxf(acc[r2], 0.f));
      }
    }
    __syncthreads();
    if (w < 2) {  // secD: sim[16][32] = hid @ caa_w2 + b2 -> s_sim (fp32)
      const int n = w * 16 + ln16;
      const float bias = p.caa_b2[n];
      f32x4 acc = {bias, bias, bias, bias};
#pragma unroll
      for (int kk = 0; kk < 4; ++kk) {
        const u16x8 a = *(const u16x8*)&s_hidb[ln16 * 128 + kk * 32 + k0];
        const u16x8 bb = *(const u16x8*)&s_wTC[n * 128 + kk * 32 + k0];
        MFMA(acc, a, bb);
      }
      MFMA_FENCE(acc);
#pragma unroll
      for (int r2 = 0; r2 < 4; ++r2) s_sim[(kg * 4 + r2) * 33 + n] = acc[r2];
    }
    __syncthreads();
    if (t < 64) {  // secE: softmax + ca + (im chain | ep chain) on wave0
      const int h = t & 31;
      float mx = -1e30f;
#pragma unroll
      for (int k = 0; k < 16; ++k) mx = fmaxf(mx, s_sim[k * 33 + h]);
      float sum = 0.f, o = 0.f;
#pragma unroll
      for (int k = 0; k < 16; ++k) {
        const float e = __expf(s_sim[k * 33 + h] - mx);
        sum += e;
        o = fmaf(e, s_u[512 + k * 32 + h] + s_rpe[k * 33 + h], o);
      }
      const float ca = o / sum;
      if (s < 8) {
        float a = p.im_b1[h];
        for (int i2 = 0; i2 < 32; ++i2) a = fmaf(__shfl(ca, i2), p.im_w1[i2 * 32 + h], a);
        const float m1 = fmaxf(a, 0.f);
        a = p.im_b2[h];
        for (int i2 = 0; i2 < 32; ++i2) a = fmaf(__shfl(m1, i2), p.im_w2[i2 * 32 + h], a);
        const float m2 = fmaxf(a, 0.f);
        float p0 = m2 * p.im_w3[h * 3 + 0];
        float p1 = m2 * p.im_w3[h * 3 + 1];
        float p2 = m2 * p.im_w3[h * 3 + 2];
#pragma unroll
        for (int m = 1; m < 32; m <<= 1) {
          p0 += __shfl_xor(p0, m, 32);
          p1 += __shfl_xor(p1, m, 32);
          p2 += __shfl_xor(p2, m, 32);
        }
        p0 += p.im_b3[0]; p1 += p.im_b3[1]; p2 += p.im_b3[2];
        const float step = sqrtf(p0 * p0 + p1 * p1 + p2 * p2);
        const float cum = s_cum;
        const float opc0 = s_qry[0] * cum, opc1 = s_qry[1] * cum, opc2 = s_qry[2] * cum;
        const float inv = 1.f / step;
        const float tg0 = p0 * inv, tg1 = p1 * inv, tg2 = p2 * inv;
        if (t == 0) {
          p.o_ms[b * 8 + s] = step;
          p.o_ip[(b * 8 + s) * 3 + 0] = opc0 + p0;
          s_op[0] = opc0 + s_qry[0] * step;
        } else if (t == 1) {
          p.o_ip[(b * 8 + s) * 3 + 1] = opc1 + p1;
          s_op[1] = opc1 + s_qry[1] * step;
        } else if (t == 2) {
          p.o_ip[(b * 8 + s) * 3 + 2] = opc2 + p2;
          s_op[2] = opc2 + s_qry[2] * step;
        } else if (t == 3) {
          s_cum = cum + step;
        }
        if (t < 16) {
          p.o_cs[b * 128 + s * 16 + t] = tg0 * rv0 + tg1 * rv1 + tg2 * rv2;
        }
      } else {
        float a = p.ep_b1[h];
        for (int i2 = 0; i2 < 32; ++i2) a = fmaf(__shfl(ca, i2), p.ep_w1[i2 * 32 + h], a);
        a = fmaf(s_qry[0], p.ep_w1[1024 + h], a);
        a = fmaf(s_qry[1], p.ep_w1[1056 + h], a);
        a = fmaf(s_qry[2], p.ep_w1[1088 + h], a);
        const float e1 = fmaxf(a, 0.f);
        a = p.ep_b2[h];
        for (int i2 = 0; i2 < 32; ++i2) a = fmaf(__shfl(e1, i2), p.ep_w2[i2 * 32 + h], a);
        const float e2 = fmaxf(a, 0.f);
        float pp = e2 * p.ep_w3[h];
#pragma unroll
        for (int m = 1; m < 32; m <<= 1) pp += __shfl_xor(pp, m, 32);
        if (t == 0) {
          p.o_eps[b] = pp + p.ep_b3[0];
          p.o_cum[b] = s_cum;
        }
      }
    }
    __syncthreads();
  }
}

extern "C" void kernel_launch(void* const* d_in, const int* in_sizes, int n_in,
                              void* d_out, int out_size, void* d_ws, size_t ws_size,
                              hipStream_t stream) {
  Params p;
  const float** f = (const float**)(void*)&p;
  for (int i = 0; i < 43; ++i) f[i] = (const float*)d_in[i];
  float* out = (float*)d_out;
  p.o_ld  = out;
  p.o_ms  = out + OFF_MS;
  p.o_cs  = out + OFF_CS;
  p.o_ip  = out + OFF_IP;
  p.o_cum = out + OFF_CUM;
  p.o_eps = out + OFF_EPS;
  puray_kernel<<<dim3(4096), dim3(256), 0, stream>>>(p);
}

// Round 10
// 783.071 us; speedup vs baseline: 5.8306x; 1.1147x over previous
//
#include <hip/hip_runtime.h>

// Problem constants: B=4096, K=16, H=32, HM=128, STEPS=8
#define OFF_MS  524288
#define OFF_CS  557056
#define OFF_IP  1081344
#define OFF_CUM 1179648
#define OFF_EPS 1183744

// Padded LDS row strides (u16 units): break the D=128 bank-0 pathology.
// 136u16=272B=68dw -> +4 banks/row (2-way, free). 40u16=80B=20dw -> 8 banks.
#define HSTR 136
#define BSTR 40

struct Params {
  const float *knn, *query, *fw1, *fb1, *fw2, *fb2, *fw3, *fb3, *qkv_w,
    *ptp_w1, *ptp_b1, *ptp_w2, *ptp_b2, *pta_w1, *pta_b1, *pta_w2, *pta_b2,
    *caq_w, *caq_b, *cak_w, *cak_b, *cav_w, *cav_b,
    *cap_w1, *cap_b1, *cap_w2, *cap_b2, *caa_w1, *caa_b1, *caa_w2, *caa_b2,
    *im_w1, *im_b1, *im_w2, *im_b2, *im_w3, *im_b3,
    *ep_w1, *ep_b1, *ep_w2, *ep_b2, *ep_w3, *ep_b3;
  float *o_ld, *o_ms, *o_cs, *o_ip, *o_cum, *o_eps;
};
static_assert(sizeof(Params) == 49 * sizeof(void*), "Params layout");

typedef float f32x4 __attribute__((ext_vector_type(4)));
typedef unsigned short u16x8 __attribute__((ext_vector_type(8)));

__device__ __forceinline__ unsigned short f2b(float x) {  // fp32->bf16 RNE
  unsigned u = __float_as_uint(x);
  u += 0x7fffu + ((u >> 16) & 1u);
  return (unsigned short)(u >> 16);
}
__device__ __forceinline__ unsigned pack2(float lo, float hi) {
  return (unsigned)f2b(lo) | ((unsigned)f2b(hi) << 16);
}

#define MFMA(acc, a, bb) \
  asm volatile("s_nop 2\n\tv_mfma_f32_16x16x32_bf16 %0, %1, %2, %0" \
               : "+v"(acc) : "v"(a), "v"(bb))
#define MFMA_FENCE(acc) asm volatile("s_nop 7\n\ts_nop 7" : "+v"(acc))

// Round-9 MFMA kernel + LDS padding (the only change). (256,2): the only
// no-spill config on this toolchain (rounds 2/3/6/8).
__launch_bounds__(256, 2)
__global__ void puray_kernel(Params p) {
  const int b = blockIdx.x;
  const int t = threadIdx.x;
  const int w = t >> 6, l = t & 63;
  const int ln16 = l & 15, kg = l >> 4, k0 = kg * 8;

  __shared__ __align__(16) unsigned short s_wTA[32 * HSTR];  // [n][k] ptp_w2T -> cap_w2T
  __shared__ __align__(16) unsigned short s_wTB[128 * BSTR]; // [n][k] pta_w1T -> caa_w1T
  __shared__ __align__(16) unsigned short s_wTC[32 * HSTR];  // [n][k] pta_w2T -> caa_w2T
  __shared__ __align__(16) unsigned short s_hidb[32 * HSTR]; // bf16 act [row][128+pad]
  __shared__ __align__(16) unsigned short s_simb[32 * BSTR]; // bf16 act [row][32+pad]
  __shared__ float s_rpe[32 * 33];
  __shared__ float s_sim[32 * 33];
  __shared__ float s_v[512], s_feats[512];
  __shared__ float s_u[1024];
  __shared__ float s_coords[48], s_relv[48], s_reld[16];
  __shared__ float s_qry[3], s_op[3], s_qq[32];
  __shared__ float s_cum;

  // ---- stage: transpose+convert phase-C weights to bf16 [N][K] (padded) ----
#pragma unroll 4
  for (int m = 0; m < 16; ++m) {
    const int idx = t + 256 * m;
    { const int n = idx >> 7, k = idx & 127;
      const unsigned short a = f2b(p.ptp_w2[k * 32 + n]);
      const unsigned short c = f2b(p.pta_w2[k * 32 + n]);
      s_wTA[n * HSTR + k] = a;
      s_wTC[n * HSTR + k] = c; }
    { const int n = idx >> 5, k = idx & 31;
      s_wTB[n * BSTR + k] = f2b(p.pta_w1[k * 128 + n]); }
  }
  if (t < 48) s_coords[t] = p.knn[b * 48 + t];
  else if (t < 51) s_qry[t - 48] = p.query[b * 3 + (t - 48)];
  else if (t == 51) s_cum = 0.f;
  else if (t < 55) s_op[t - 52] = 0.f;
  __syncthreads();

  // ---- Phase A: feats (scratch: s_rpe=h1, s_sim=h2) ----
#pragma unroll
  for (int m = 0; m < 2; ++m) {
    const int l2 = t + 256 * m, pp = l2 >> 5, jj = l2 & 31;
    float a = p.fb1[jj];
#pragma unroll
    for (int c = 0; c < 3; ++c) a = fmaf(s_coords[pp * 3 + c], p.fw1[c * 32 + jj], a);
    s_rpe[l2] = fmaxf(a, 0.f);
  }
  __syncthreads();
#pragma unroll
  for (int m = 0; m < 2; ++m) {
    const int l2 = t + 256 * m, pp = l2 >> 5, jj = l2 & 31;
    float a = p.fb2[jj];
    for (int i = 0; i < 32; ++i) a = fmaf(s_rpe[pp * 32 + i], p.fw2[i * 32 + jj], a);
    s_sim[l2] = fmaxf(a, 0.f);
  }
  __syncthreads();
#pragma unroll
  for (int m = 0; m < 2; ++m) {
    const int l2 = t + 256 * m, pp = l2 >> 5, jj = l2 & 31;
    float a = p.fb3[jj];
    for (int i = 0; i < 32; ++i) a = fmaf(s_sim[pp * 32 + i], p.fw3[i * 32 + jj], a);
    s_feats[l2] = a;
  }
  __syncthreads();

  // ---- Phase B: qkv ----
#pragma unroll
  for (int m = 0; m < 6; ++m) {
    const int l2 = t + 256 * m, pp = l2 / 96, o = l2 % 96;
    float a = 0.f;
    for (int i = 0; i < 32; ++i) a = fmaf(s_feats[pp * 32 + i], p.qkv_w[i * 96 + o], a);
    if (o < 32) s_u[pp * 32 + o] = a;
    else if (o < 64) s_u[512 + pp * 32 + o - 32] = a;
    else s_v[pp * 32 + o - 64] = a;
  }
  __syncthreads();

  // ---- Phase C: 2 output rows per iteration, MFMA GEMMs ----
  for (int ig = 0; ig < 16; ig += 2) {
    {  // sec1a: hv[32][128] -> s_hidb (bf16)
      const int r = t >> 3;
      const int i = ig + (r >> 4), j = r & 15;
      const float r0 = s_coords[i * 3 + 0] - s_coords[j * 3 + 0];
      const float r1 = s_coords[i * 3 + 1] - s_coords[j * 3 + 1];
      const float r2 = s_coords[i * 3 + 2] - s_coords[j * 3 + 2];
      const int d0 = (t & 7) * 16;
#pragma unroll
      for (int x = 0; x < 16; x += 2) {
        const int d = d0 + x;
        const float h0v = fmaxf(fmaf(r0, p.ptp_w1[d],
                           fmaf(r1, p.ptp_w1[128 + d],
                           fmaf(r2, p.ptp_w1[256 + d], p.ptp_b1[d]))), 0.f);
        const float h1v = fmaxf(fmaf(r0, p.ptp_w1[d + 1],
                           fmaf(r1, p.ptp_w1[128 + d + 1],
                           fmaf(r2, p.ptp_w1[256 + d + 1], p.ptp_b1[d + 1]))), 0.f);
        ((unsigned*)s_hidb)[(r * HSTR + d) >> 1] = pack2(h0v, h1v);
      }
    }
    __syncthreads();
    {  // G1: rpe[32][32] = hv @ ptp_w2 + b2 ; simin = q[i]-k[j]+rpe -> s_simb
      const int mb = w >> 1, nb = w & 1, n = nb * 16 + ln16;
      const float bias = p.ptp_b2[n];
      f32x4 acc = {bias, bias, bias, bias};
#pragma unroll
      for (int kk = 0; kk < 4; ++kk) {
        const u16x8 a = *(const u16x8*)&s_hidb[(mb * 16 + ln16) * HSTR + kk * 32 + k0];
        const u16x8 bb = *(const u16x8*)&s_wTA[n * HSTR + kk * 32 + k0];
        MFMA(acc, a, bb);
      }
      MFMA_FENCE(acc);
#pragma unroll
      for (int r2 = 0; r2 < 4; ++r2) {
        const int row = mb * 16 + kg * 4 + r2;
        const float val = acc[r2];
        s_rpe[row * 33 + n] = val;
        const int i = ig + (row >> 4), j = row & 15;
        s_simb[row * BSTR + n] = f2b(s_u[i * 32 + n] - s_u[512 + j * 32 + n] + val);
      }
    }
    __syncthreads();
    {  // G2: hid[32][128] = relu(simin @ pta_w1 + b1) -> s_hidb
      const int mb = w & 1;
      const u16x8 a = *(const u16x8*)&s_simb[(mb * 16 + ln16) * BSTR + k0];
#pragma unroll
      for (int j2 = 0; j2 < 4; ++j2) {
        const int n = ((w >> 1) * 4 + j2) * 16 + ln16;
        const u16x8 bb = *(const u16x8*)&s_wTB[n * BSTR + k0];
        const float bias = p.pta_b1[n];
        f32x4 acc = {bias, bias, bias, bias};
        MFMA(acc, a, bb);
        MFMA_FENCE(acc);
#pragma unroll
        for (int r2 = 0; r2 < 4; ++r2)
          s_hidb[(mb * 16 + kg * 4 + r2) * HSTR + n] = f2b(fmaxf(acc[r2], 0.f));
      }
    }
    __syncthreads();
    {  // G3: sim[32][32] = hid @ pta_w2 + b2 -> s_sim (fp32)
      const int mb = w >> 1, nb = w & 1, n = nb * 16 + ln16;
      const float bias = p.pta_b2[n];
      f32x4 acc = {bias, bias, bias, bias};
#pragma unroll
      for (int kk = 0; kk < 4; ++kk) {
        const u16x8 a = *(const u16x8*)&s_hidb[(mb * 16 + ln16) * HSTR + kk * 32 + k0];
        const u16x8 bb = *(const u16x8*)&s_wTC[n * HSTR + kk * 32 + k0];
        MFMA(acc, a, bb);
      }
      MFMA_FENCE(acc);
#pragma unroll
      for (int r2 = 0; r2 < 4; ++r2) s_sim[(mb * 16 + kg * 4 + r2) * 33 + n] = acc[r2];
    }
    __syncthreads();
    if (t < 64) {  // sec4: softmax + weighted sum (fp32)
      const int g2 = t >> 5, h = t & 31;
      float mx = -1e30f;
#pragma unroll
      for (int j2 = 0; j2 < 16; ++j2) mx = fmaxf(mx, s_sim[(g2 * 16 + j2) * 33 + h]);
      float sum = 0.f, o = 0.f;
#pragma unroll
      for (int j2 = 0; j2 < 16; ++j2) {
        const float e = __expf(s_sim[(g2 * 16 + j2) * 33 + h] - mx);
        sum += e;
        o = fmaf(e, s_v[j2 * 32 + h] + s_rpe[(g2 * 16 + j2) * 33 + h], o);
      }
      s_feats[(ig + g2) * 32 + h] = o / sum;
    }
    __syncthreads();
  }

  // ---- restage weights (cap/caa) + hoisted kk/vv ----
#pragma unroll 4
  for (int m = 0; m < 16; ++m) {
    const int idx = t + 256 * m;
    { const int n = idx >> 7, k = idx & 127;
      const unsigned short a = f2b(p.cap_w2[k * 32 + n]);
      const unsigned short c = f2b(p.caa_w2[k * 32 + n]);
      s_wTA[n * HSTR + k] = a;
      s_wTC[n * HSTR + k] = c; }
    { const int n = idx >> 5, k = idx & 31;
      s_wTB[n * BSTR + k] = f2b(p.caa_w1[k * 128 + n]); }
  }
#pragma unroll
  for (int m = 0; m < 2; ++m) {
    const int l2 = t + 256 * m, k = l2 >> 5, h = l2 & 31;
    float akk = p.cak_b[h], avv = p.cav_b[h];
    for (int i = 0; i < 32; ++i) {
      const float f = s_feats[k * 32 + i];
      akk = fmaf(f, p.cak_w[i * 32 + h], akk);
      avv = fmaf(f, p.cav_w[i * 32 + h], avv);
    }
    s_u[k * 32 + h] = akk;
    s_u[512 + k * 32 + h] = avv;
  }
  __syncthreads();

  // ---- Phase D: 8 march steps + epilogue ----
  for (int s = 0; s <= 8; ++s) {
    float rv0 = 0.f, rv1 = 0.f, rv2 = 0.f;
    {  // secA: hv[16][128] -> s_hidb (bf16)
      const int k = t >> 4, d0 = (t & 15) * 8;
      float c0, c1, c2;
      if (s < 8) {
        c0 = s_coords[k * 3 + 0] - s_op[0];
        c1 = s_coords[k * 3 + 1] - s_op[1];
        c2 = s_coords[k * 3 + 2] - s_op[2];
      } else {
        const float rd = s_reld[k];
        c0 = s_relv[k * 3 + 0] * rd; c1 = s_relv[k * 3 + 1] * rd; c2 = s_relv[k * 3 + 2] * rd;
      }
#pragma unroll
      for (int x = 0; x < 8; x += 2) {
        const int d = d0 + x;
        const float h0v = fmaxf(fmaf(c0, p.cap_w1[d],
                           fmaf(c1, p.cap_w1[128 + d],
                           fmaf(c2, p.cap_w1[256 + d], p.cap_b1[d]))), 0.f);
        const float h1v = fmaxf(fmaf(c0, p.cap_w1[d + 1],
                           fmaf(c1, p.cap_w1[128 + d + 1],
                           fmaf(c2, p.cap_w1[256 + d + 1], p.cap_b1[d + 1]))), 0.f);
        ((unsigned*)s_hidb)[(k * HSTR + d) >> 1] = pack2(h0v, h1v);
      }
    }
    if (t < 64) {  // wave0: rel/o_ld + shuffle feat_mlp chain -> s_qq
      const int h = t & 31;
      if (s < 8 && t < 16) {
        const float r0 = s_coords[t * 3 + 0] - s_op[0];
        const float r1 = s_coords[t * 3 + 1] - s_op[1];
        const float r2 = s_coords[t * 3 + 2] - s_op[2];
        const float rd = sqrtf(r0 * r0 + r1 * r1 + r2 * r2);
        const float inv = 1.f / rd;
        rv0 = r0 * inv; rv1 = r1 * inv; rv2 = r2 * inv;
        s_reld[t] = rd;
        s_relv[t * 3 + 0] = rv0; s_relv[t * 3 + 1] = rv1; s_relv[t * 3 + 2] = rv2;
        p.o_ld[b * 128 + s * 16 + t] = rd;
      }
      float opc0, opc1, opc2;
      if (s < 8) {
        const float cum = s_cum;
        opc0 = s_qry[0] * cum; opc1 = s_qry[1] * cum; opc2 = s_qry[2] * cum;
      } else {
        opc0 = s_op[0]; opc1 = s_op[1]; opc2 = s_op[2];
      }
      float v1 = fmaxf(fmaf(opc0, p.fw1[h],
                    fmaf(opc1, p.fw1[32 + h],
                    fmaf(opc2, p.fw1[64 + h], p.fb1[h]))), 0.f);
      float a = p.fb2[h];
      for (int i2 = 0; i2 < 32; ++i2) a = fmaf(__shfl(v1, i2), p.fw2[i2 * 32 + h], a);
      const float v2 = fmaxf(a, 0.f);
      a = p.fb3[h];
      for (int i2 = 0; i2 < 32; ++i2) a = fmaf(__shfl(v2, i2), p.fw3[i2 * 32 + h], a);
      const float opf = a;
      a = p.caq_b[h];
      for (int i2 = 0; i2 < 32; ++i2) a = fmaf(__shfl(opf, i2), p.caq_w[i2 * 32 + h], a);
      if (t < 32) s_qq[h] = a;
    }
    __syncthreads();
    if (w < 2) {  // secB: pe[16][32] = hv @ cap_w2 + b2; fused ain -> s_simb
      const int n = w * 16 + ln16;
      const float bias = p.cap_b2[n];
      f32x4 acc = {bias, bias, bias, bias};
#pragma unroll
      for (int kk = 0; kk < 4; ++kk) {
        const u16x8 a = *(const u16x8*)&s_hidb[ln16 * HSTR + kk * 32 + k0];
        const u16x8 bb = *(const u16x8*)&s_wTA[n * HSTR + kk * 32 + k0];
        MFMA(acc, a, bb);
      }
      MFMA_FENCE(acc);
#pragma unroll
      for (int r2 = 0; r2 < 4; ++r2) {
        const int row = kg * 4 + r2;
        const float pe = acc[r2];
        s_rpe[row * 33 + n] = pe;
        s_simb[row * BSTR + n] = f2b(s_qq[n] - s_u[row * 32 + n] + pe);
      }
    }
    __syncthreads();
    {  // secC: hid[16][128] = relu(ain @ caa_w1 + b1) -> s_hidb
      const u16x8 a = *(const u16x8*)&s_simb[ln16 * BSTR + k0];
#pragma unroll
      for (int j2 = 0; j2 < 2; ++j2) {
        const int n = (w * 2 + j2) * 16 + ln16;
        const u16x8 bb = *(const u16x8*)&s_wTB[n * BSTR + k0];
        const float bias = p.caa_b1[n];
        f32x4 acc = {bias, bias, bias, bias};
        MFMA(acc, a, bb);
        MFMA_FENCE(acc);
#pragma unroll
        for (int r2 = 0; r2 < 4; ++r2)
          s_hidb[(kg * 4 + r2) * HSTR + n] = f2b(fmaxf(acc[r2], 0.f));
      }
    }
    __syncthreads();
    if (w < 2) {  // secD: sim[16][32] = hid @ caa_w2 + b2 -> s_sim (fp32)
      const int n = w * 16 + ln16;
      const float bias = p.caa_b2[n];
      f32x4 acc = {bias, bias, bias, bias};
#pragma unroll
      for (int kk = 0; kk < 4; ++kk) {
        const u16x8 a = *(const u16x8*)&s_hidb[ln16 * HSTR + kk * 32 + k0];
        const u16x8 bb = *(const u16x8*)&s_wTC[n * HSTR + kk * 32 + k0];
        MFMA(acc, a, bb);
      }
      MFMA_FENCE(acc);
#pragma unroll
      for (int r2 = 0; r2 < 4; ++r2) s_sim[(kg * 4 + r2) * 33 + n] = acc[r2];
    }
    __syncthreads();
    if (t < 64) {  // secE: softmax + ca + (im chain | ep chain) on wave0
      const int h = t & 31;
      float mx = -1e30f;
#pragma unroll
      for (int k = 0; k < 16; ++k) mx = fmaxf(mx, s_sim[k * 33 + h]);
      float sum = 0.f, o = 0.f;
#pragma unroll
      for (int k = 0; k < 16; ++k) {
        const float e = __expf(s_sim[k * 33 + h] - mx);
        sum += e;
        o = fmaf(e, s_u[512 + k * 32 + h] + s_rpe[k * 33 + h], o);
      }
      const float ca = o / sum;
      if (s < 8) {
        float a = p.im_b1[h];
        for (int i2 = 0; i2 < 32; ++i2) a = fmaf(__shfl(ca, i2), p.im_w1[i2 * 32 + h], a);
        const float m1 = fmaxf(a, 0.f);
        a = p.im_b2[h];
        for (int i2 = 0; i2 < 32; ++i2) a = fmaf(__shfl(m1, i2), p.im_w2[i2 * 32 + h], a);
        const float m2 = fmaxf(a, 0.f);
        float p0 = m2 * p.im_w3[h * 3 + 0];
        float p1 = m2 * p.im_w3[h * 3 + 1];
        float p2 = m2 * p.im_w3[h * 3 + 2];
#pragma unroll
        for (int m = 1; m < 32; m <<= 1) {
          p0 += __shfl_xor(p0, m, 32);
          p1 += __shfl_xor(p1, m, 32);
          p2 += __shfl_xor(p2, m, 32);
        }
        p0 += p.im_b3[0]; p1 += p.im_b3[1]; p2 += p.im_b3[2];
        const float step = sqrtf(p0 * p0 + p1 * p1 + p2 * p2);
        const float cum = s_cum;
        const float opc0 = s_qry[0] * cum, opc1 = s_qry[1] * cum, opc2 = s_qry[2] * cum;
        const float inv = 1.f / step;
        const float tg0 = p0 * inv, tg1 = p1 * inv, tg2 = p2 * inv;
        if (t == 0) {
          p.o_ms[b * 8 + s] = step;
          p.o_ip[(b * 8 + s) * 3 + 0] = opc0 + p0;
          s_op[0] = opc0 + s_qry[0] * step;
        } else if (t == 1) {
          p.o_ip[(b * 8 + s) * 3 + 1] = opc1 + p1;
          s_op[1] = opc1 + s_qry[1] * step;
        } else if (t == 2) {
          p.o_ip[(b * 8 + s) * 3 + 2] = opc2 + p2;
          s_op[2] = opc2 + s_qry[2] * step;
        } else if (t == 3) {
          s_cum = cum + step;
        }
        if (t < 16) {
          p.o_cs[b * 128 + s * 16 + t] = tg0 * rv0 + tg1 * rv1 + tg2 * rv2;
        }
      } else {
        float a = p.ep_b1[h];
        for (int i2 = 0; i2 < 32; ++i2) a = fmaf(__shfl(ca, i2), p.ep_w1[i2 * 32 + h], a);
        a = fmaf(s_qry[0], p.ep_w1[1024 + h], a);
        a = fmaf(s_qry[1], p.ep_w1[1056 + h], a);
        a = fmaf(s_qry[2], p.ep_w1[1088 + h], a);
        const float e1 = fmaxf(a, 0.f);
        a = p.ep_b2[h];
        for (int i2 = 0; i2 < 32; ++i2) a = fmaf(__shfl(e1, i2), p.ep_w2[i2 * 32 + h], a);
        const float e2 = fmaxf(a, 0.f);
        float pp = e2 * p.ep_w3[h];
#pragma unroll
        for (int m = 1; m < 32; m <<= 1) pp += __shfl_xor(pp, m, 32);
        if (t == 0) {
          p.o_eps[b] = pp + p.ep_b3[0];
          p.o_cum[b] = s_cum;
        }
      }
    }
    __syncthreads();
  }
}

extern "C" void kernel_launch(void* const* d_in, const int* in_sizes, int n_in,
                              void* d_out, int out_size, void* d_ws, size_t ws_size,
                              hipStream_t stream) {
  Params p;
  const float** f = (const float**)(void*)&p;
  for (int i = 0; i < 43; ++i) f[i] = (const float*)d_in[i];
  float* out = (float*)d_out;
  p.o_ld  = out;
  p.o_ms  = out + OFF_MS;
  p.o_cs  = out + OFF_CS;
  p.o_ip  = out + OFF_IP;
  p.o_cum = out + OFF_CUM;
  p.o_eps = out + OFF_EPS;
  puray_kernel<<<dim3(4096), dim3(256), 0, stream>>>(p);
}